// Round 4
// baseline (85.656 us; speedup 1.0000x reference)
//
#include <hip/hip_runtime.h>
#include <math.h>

#define ALPHA 0.1f
#define EPS 1e-8f

constexpr int B = 2048;
constexpr int C = 256;
constexpr int F = 256;
constexpr int TB = 8;             // B-rows per block in main kernel
constexpr int NF4 = F / 4;        // 64 float4 groups
constexpr int HALF_F4 = NF4 / 2;  // 32 per half-block

// ---------------------------------------------------------------------------
// prep: per-class precompute + passthrough copies.
//   grid = C blocks, block = F threads.
//   ivq  = 1/(v+eps)        in [f/4][c][f%4] packed-transposed layout
//   mvq  = -2*m/(v+eps)     same layout (sign/scale folded into the FMA)
//   msq  = sum_f m^2/(v+eps),  invden = 1/(det^2+eps)
// ---------------------------------------------------------------------------
__global__ __launch_bounds__(256) void prep_kernel(
    const float* __restrict__ means, const float* __restrict__ vars_,
    float* __restrict__ ivq, float* __restrict__ mvq,
    float* __restrict__ msq, float* __restrict__ invden,
    float* __restrict__ out_means, float* __restrict__ out_vars)
{
    const int c = blockIdx.x;
    const int f = threadIdx.x;
    const float v = vars_[c * F + f];
    const float m = means[c * F + f];
    const float iv = 1.0f / (v + EPS);

    const int idx = (f >> 2) * (C * 4) + c * 4 + (f & 3);
    ivq[idx] = iv;
    mvq[idx] = -2.0f * m * iv;

    out_means[c * F + f] = m;
    out_vars[c * F + f]  = v;

    float s = m * m * iv;
    float p = v;
    #pragma unroll
    for (int off = 32; off > 0; off >>= 1) {
        s += __shfl_down(s, off);
        p *= __shfl_down(p, off);
    }
    __shared__ float ss[4], pp[4];
    const int wave = f >> 6, lane = f & 63;
    if (lane == 0) { ss[wave] = s; pp[wave] = p; }
    __syncthreads();
    if (f == 0) {
        const float st = ss[0] + ss[1] + ss[2] + ss[3];
        const float pt = pp[0] * pp[1] * pp[2] * pp[3];  // det of diagonal cov
        msq[c]    = st;
        invden[c] = 1.0f / (pt * pt + EPS);
    }
}

// ---------------------------------------------------------------------------
// main: distances + softmax-ratio loss. LDS-free inner loop.
//   grid = B/TB = 256 blocks, block = 512 threads (8 waves, 2/SIMD).
//   thread = (half, class): half 0 -> features [0,128), half 1 -> [128,256).
//   feat reads are BLOCK-UNIFORM float4 loads (scalar-pipe s_load / L1
//   broadcast) -> zero LDS traffic in the hot loop. Per (elem,row):
//   t = fma(iv, x, -2*m*iv); acc = fma(x, t, acc)  -- x is the SGPR operand.
//   Halves combine through a small LDS buffer afterwards.
// ---------------------------------------------------------------------------
__global__ __launch_bounds__(512) void lgm_main(
    const float* __restrict__ feat, const int* __restrict__ labels,
    const float* __restrict__ ivq, const float* __restrict__ mvq,
    const float* __restrict__ msq, const float* __restrict__ invden,
    float* __restrict__ loss)
{
    __shared__ float comb[TB][C];      // 8 KiB: half-1 partial sums
    __shared__ int   slab[TB];
    __shared__ float wsum[TB][4];
    __shared__ float clsp[TB];

    const int tid  = threadIdx.x;
    const int cls  = tid & (C - 1);
    const int half = tid >> 8;         // 0 or 1
    const int b0   = blockIdx.x * TB;

    if (tid < TB) slab[tid] = labels[b0 + tid];

    float acc[TB];
    #pragma unroll
    for (int i = 0; i < TB; ++i) acc[i] = 0.0f;

    const float4* __restrict__ iv4p  = (const float4*)ivq;
    const float4* __restrict__ mv4p  = (const float4*)mvq;
    const float4* __restrict__ feat4 = (const float4*)feat;

    #pragma unroll 2
    for (int k = 0; k < HALF_F4; ++k) {
        const int f4 = half * HALF_F4 + k;
        const float4 iv = iv4p[f4 * C + cls];
        const float4 mv = mv4p[f4 * C + cls];
        #pragma unroll
        for (int i = 0; i < TB; ++i) {
            const float4 x = feat4[(b0 + i) * NF4 + f4];   // block-uniform
            float a = acc[i];
            a = fmaf(x.x, fmaf(iv.x, x.x, mv.x), a);
            a = fmaf(x.y, fmaf(iv.y, x.y, mv.y), a);
            a = fmaf(x.z, fmaf(iv.z, x.z, mv.z), a);
            a = fmaf(x.w, fmaf(iv.w, x.w, mv.w), a);
            acc[i] = a;
        }
    }

    __syncthreads();                   // slab visible; comb safe to write
    if (half == 1) {
        #pragma unroll
        for (int i = 0; i < TB; ++i) comb[i][cls] = acc[i];  // conflict-free
    }
    __syncthreads();

    float pv[TB];
    const int lane = tid & 63, wave = tid >> 6;
    if (half == 0) {
        const float mq  = msq[cls];
        const float idn = invden[cls];
        #pragma unroll
        for (int i = 0; i < TB; ++i) {
            const float dist = 0.5f * (acc[i] + comb[i][cls] + mq);
            const float adj  = (slab[i] == cls) ? dist * (1.0f + ALPHA) : dist;
            pv[i] = expf(-adj) * idn;
            if (slab[i] == cls) clsp[i] = pv[i];
        }
    } else {
        #pragma unroll
        for (int i = 0; i < TB; ++i) pv[i] = 0.0f;
    }

    #pragma unroll
    for (int i = 0; i < TB; ++i) {
        float s = pv[i];
        #pragma unroll
        for (int off = 32; off > 0; off >>= 1) s += __shfl_down(s, off);
        if (half == 0 && lane == 0) wsum[i][wave] = s;
    }
    __syncthreads();

    if (tid < TB) {
        const float s = wsum[tid][0] + wsum[tid][1] + wsum[tid][2] + wsum[tid][3];
        loss[b0 + tid] = -logf(clsp[tid] / (s + EPS) + EPS);
    }
}

// ---------------------------------------------------------------------------
extern "C" void kernel_launch(void* const* d_in, const int* in_sizes, int n_in,
                              void* d_out, int out_size, void* d_ws, size_t ws_size,
                              hipStream_t stream) {
    const float* feat   = (const float*)d_in[0];
    const int*   labels = (const int*)  d_in[1];
    const float* means  = (const float*)d_in[2];
    const float* vars_  = (const float*)d_in[3];

    float* out       = (float*)d_out;
    float* loss      = out;                 // [B]
    float* out_means = out + B;             // [C*F]
    float* out_vars  = out + B + C * F;     // [C*F]

    float* ws     = (float*)d_ws;
    float* ivq    = ws;                     // [F/4][C][4] = C*F
    float* mvq    = ivq + C * F;            // C*F
    float* msq    = mvq + C * F;            // [C]
    float* invden = msq + C;                // [C]

    prep_kernel<<<C, 256, 0, stream>>>(means, vars_, ivq, mvq, msq, invden,
                                       out_means, out_vars);
    lgm_main<<<B / TB, 512, 0, stream>>>(feat, labels, ivq, mvq, msq, invden, loss);
}

// Round 5
// 79.037 us; speedup vs baseline: 1.0837x; 1.0837x over previous
//
#include <hip/hip_runtime.h>
#include <math.h>

#define ALPHA 0.1f
#define EPS 1e-8f

constexpr int B = 2048;
constexpr int C = 256;
constexpr int F = 256;
constexpr int TB = 8;             // B-rows per block in main kernel
constexpr int NF4 = F / 4;        // 64 float4 groups
constexpr int HALF_F4 = NF4 / 2;  // 32 per half-block

// ---------------------------------------------------------------------------
// prep: per-class precompute + passthrough copies.
//   grid = C blocks, block = F threads.
//   ivq  = 1/(v+eps)        in [f/4][c][f%4] packed-transposed layout
//   mvq  = -2*m/(v+eps)     same layout (sign/scale folded into the FMA)
//   msq  = sum_f m^2/(v+eps),  invden = 1/(det^2+eps)
// ---------------------------------------------------------------------------
__global__ __launch_bounds__(256) void prep_kernel(
    const float* __restrict__ means, const float* __restrict__ vars_,
    float* __restrict__ ivq, float* __restrict__ mvq,
    float* __restrict__ msq, float* __restrict__ invden,
    float* __restrict__ out_means, float* __restrict__ out_vars)
{
    const int c = blockIdx.x;
    const int f = threadIdx.x;
    const float v = vars_[c * F + f];
    const float m = means[c * F + f];
    const float iv = 1.0f / (v + EPS);

    const int idx = (f >> 2) * (C * 4) + c * 4 + (f & 3);
    ivq[idx] = iv;
    mvq[idx] = -2.0f * m * iv;

    out_means[c * F + f] = m;
    out_vars[c * F + f]  = v;

    float s = m * m * iv;
    float p = v;
    #pragma unroll
    for (int off = 32; off > 0; off >>= 1) {
        s += __shfl_down(s, off);
        p *= __shfl_down(p, off);
    }
    __shared__ float ss[4], pp[4];
    const int wave = f >> 6, lane = f & 63;
    if (lane == 0) { ss[wave] = s; pp[wave] = p; }
    __syncthreads();
    if (f == 0) {
        const float st = ss[0] + ss[1] + ss[2] + ss[3];
        const float pt = pp[0] * pp[1] * pp[2] * pp[3];  // det of diagonal cov
        msq[c]    = st;
        invden[c] = 1.0f / (pt * pt + EPS);
    }
}

// ---------------------------------------------------------------------------
// main: distances + softmax-ratio loss.
//   grid = B/TB = 256 blocks, block = 512 threads (8 waves/CU, 2/SIMD).
//   thread = (half, class): half 0 handles features [0,128), half 1 [128,256).
//   Inner loop per f4: 2 coalesced float4 loads (iv, mv) + 8 ds_read_b128
//   same-address broadcasts (feat rows, conflict-free) + 64 FMAs:
//   acc += x*(iv*x + (-2*m*iv)).  Halves combine through reused sfeat LDS.
// ---------------------------------------------------------------------------
__global__ __launch_bounds__(512) void lgm_main(
    const float* __restrict__ feat, const int* __restrict__ labels,
    const float* __restrict__ ivq, const float* __restrict__ mvq,
    const float* __restrict__ msq, const float* __restrict__ invden,
    float* __restrict__ loss)
{
    __shared__ float sfeat[TB][F];     // 8 KiB; reused as combine buffer
    __shared__ int   slab[TB];
    __shared__ float wsum[TB][4];
    __shared__ float clsp[TB];

    const int tid  = threadIdx.x;
    const int cls  = tid & (C - 1);
    const int half = tid >> 8;         // 0 or 1
    const int b0   = blockIdx.x * TB;

    // stage 8 feat rows: 512 threads x float4 = 8 KiB, fully coalesced
    ((float4*)sfeat)[tid] = ((const float4*)(feat + b0 * F))[tid];
    if (tid < TB) { slab[tid] = labels[b0 + tid]; clsp[tid] = 0.0f; }
    __syncthreads();

    float acc[TB];
    #pragma unroll
    for (int i = 0; i < TB; ++i) acc[i] = 0.0f;

    const float4* __restrict__ iv4p = (const float4*)ivq;
    const float4* __restrict__ mv4p = (const float4*)mvq;

    #pragma unroll 4
    for (int k = 0; k < HALF_F4; ++k) {
        const int f4 = half * HALF_F4 + k;
        const float4 iv = iv4p[f4 * C + cls];
        const float4 mv = mv4p[f4 * C + cls];
        #pragma unroll
        for (int i = 0; i < TB; ++i) {
            const float4 x = *(const float4*)&sfeat[i][f4 * 4];  // b128 broadcast
            float a = acc[i];
            a = fmaf(x.x, fmaf(iv.x, x.x, mv.x), a);
            a = fmaf(x.y, fmaf(iv.y, x.y, mv.y), a);
            a = fmaf(x.z, fmaf(iv.z, x.z, mv.z), a);
            a = fmaf(x.w, fmaf(iv.w, x.w, mv.w), a);
            acc[i] = a;
        }
    }

    // combine the two F-halves through LDS (sfeat no longer needed)
    __syncthreads();
    if (half == 1) {
        #pragma unroll
        for (int i = 0; i < TB; ++i) sfeat[i][cls] = acc[i];   // conflict-free
    }
    __syncthreads();

    float pv[TB];
    const int lane = tid & 63, wave = tid >> 6;
    if (half == 0) {
        const float mq  = msq[cls];
        const float idn = invden[cls];
        #pragma unroll
        for (int i = 0; i < TB; ++i) {
            const float dist = 0.5f * (acc[i] + sfeat[i][cls] + mq);
            const float adj  = (slab[i] == cls) ? dist * (1.0f + ALPHA) : dist;
            pv[i] = expf(-adj) * idn;
            if (slab[i] == cls) clsp[i] = pv[i];
        }
    } else {
        #pragma unroll
        for (int i = 0; i < TB; ++i) pv[i] = 0.0f;
    }

    #pragma unroll
    for (int i = 0; i < TB; ++i) {
        float s = pv[i];
        #pragma unroll
        for (int off = 32; off > 0; off >>= 1) s += __shfl_down(s, off);
        if (half == 0 && lane == 0) wsum[i][wave] = s;
    }
    __syncthreads();

    if (tid < TB) {
        const float s = wsum[tid][0] + wsum[tid][1] + wsum[tid][2] + wsum[tid][3];
        loss[b0 + tid] = -logf(clsp[tid] / (s + EPS) + EPS);
    }
}

// ---------------------------------------------------------------------------
extern "C" void kernel_launch(void* const* d_in, const int* in_sizes, int n_in,
                              void* d_out, int out_size, void* d_ws, size_t ws_size,
                              hipStream_t stream) {
    const float* feat   = (const float*)d_in[0];
    const int*   labels = (const int*)  d_in[1];
    const float* means  = (const float*)d_in[2];
    const float* vars_  = (const float*)d_in[3];

    float* out       = (float*)d_out;
    float* loss      = out;                 // [B]
    float* out_means = out + B;             // [C*F]
    float* out_vars  = out + B + C * F;     // [C*F]

    float* ws     = (float*)d_ws;
    float* ivq    = ws;                     // [F/4][C][4] = C*F
    float* mvq    = ivq + C * F;            // C*F
    float* msq    = mvq + C * F;            // [C]
    float* invden = msq + C;                // [C]

    prep_kernel<<<C, 256, 0, stream>>>(means, vars_, ivq, mvq, msq, invden,
                                       out_means, out_vars);
    lgm_main<<<B / TB, 512, 0, stream>>>(feat, labels, ivq, mvq, msq, invden, loss);
}